// Round 17
// baseline (718.750 us; speedup 1.0000x reference)
//
#include <hip/hip_runtime.h>
#include <stdint.h>

#define TT 512

typedef __fp16   f16x8  __attribute__((ext_vector_type(8)));
typedef float    f32x4  __attribute__((ext_vector_type(4)));
typedef __fp16   fp16x2 __attribute__((ext_vector_type(2)));
typedef uint32_t u32x2  __attribute__((ext_vector_type(2)));

__device__ __forceinline__ f32x4 mfma16(f16x8 a, f16x8 b, f32x4 c) {
    return __builtin_amdgcn_mfma_f32_16x16x32_f16(a, b, c, 0, 0, 0);
}
__device__ __forceinline__ uint32_t pkf16(float a, float b) {
    fp16x2 h = __builtin_amdgcn_cvt_pkrtz(a, b);
    return __builtin_bit_cast(uint32_t, h);
}

#define REP8(M) M(0)M(1)M(2)M(3)M(4)M(5)M(6)M(7)

// A-operand gather with per-column scale SC (weights transposed, z^T form):
// A[m=16T+l15][k=32F+8q+j] = SRC[k][16T+l15] * SC
#define GA(SRC, T, F, SC) (f16x8){ \
  (__fp16)((SRC)[(32*(F)+8*quad+0)*256 + 16*(T)+l15] * (SC)), \
  (__fp16)((SRC)[(32*(F)+8*quad+1)*256 + 16*(T)+l15] * (SC)), \
  (__fp16)((SRC)[(32*(F)+8*quad+2)*256 + 16*(T)+l15] * (SC)), \
  (__fp16)((SRC)[(32*(F)+8*quad+3)*256 + 16*(T)+l15] * (SC)), \
  (__fp16)((SRC)[(32*(F)+8*quad+4)*256 + 16*(T)+l15] * (SC)), \
  (__fp16)((SRC)[(32*(F)+8*quad+5)*256 + 16*(T)+l15] * (SC)), \
  (__fp16)((SRC)[(32*(F)+8*quad+6)*256 + 16*(T)+l15] * (SC)), \
  (__fp16)((SRC)[(32*(F)+8*quad+7)*256 + 16*(T)+l15] * (SC)) }

// Wave (l,h) owns zcols {64g + 32h + 16q' .. +15}: local j = 2g+q' -> tile Tg.
// Gate index = j>>1 (0:i 1:f 2:g 3:o). i/f/o columns pre-scaled by -log2e at
// load time; bias pre-scaled in LDS table (bs) -- R22-verified identical math.
#define DECLT(j) f16x8 uA##j##_0, uA##j##_1, wA##j##_0, wA##j##_1;
#define LOADT(j) { \
  const int Tg_ = ((j)>>1)*4 + 2*h + ((j)&1); \
  const float sc_ = (((j)>>1) == 2) ? 1.0f : -1.4426950408889634f; \
  uA##j##_0 = GA(Uw, Tg_, 0, sc_); uA##j##_1 = GA(Uw, Tg_, 1, sc_); \
  if (l > 0) { wA##j##_0 = GA(Wsrc, Tg_, 0, sc_); wA##j##_1 = GA(Wsrc, Tg_, 1, sc_); } \
  else { wA##j##_0 = __builtin_bit_cast(f16x8, (f32x4){ \
           Wx0[16*Tg_+4*quad+0] * sc_, Wx0[16*Tg_+4*quad+1] * sc_, \
           Wx0[16*Tg_+4*quad+2] * sc_, Wx0[16*Tg_+4*quad+3] * sc_ }); \
         wA##j##_1 = wA##j##_0; } }

// R27 SINGLE-ACC W-PREFETCH: U(t) accumulates into acc, gates(t) consume acc,
// then WPRE OVERWRITES acc with bias + W*in(t+1) (bias rides C from LDS).
// No second accumulator set -- R16's spill cause (wacc +32 VGPR) is removed.
// The W burst + its bias/xB ds_reads are independent of gates -> scheduler can
// interleave gate trans ops with W MFMA issue (fills both pipes per wave).
#define MUA(j) acc##j = mfma16(uA##j##_0, hB0, acc##j);
#define MUB(j) acc##j = mfma16(uA##j##_1, hB1, acc##j);
#define WPRE(j) { \
  const int Tg_ = ((j)>>1)*4 + 2*h + ((j)&1); \
  f32x4 b_ = *(const f32x4*)(bsl + 16*Tg_ + 4*quad); \
  acc##j = mfma16(wA##j##_0, xBp0, b_); \
  acc##j = mfma16(wA##j##_1, xBp1, acc##j); }
#define WPREX(j) { \
  const int Tg_ = ((j)>>1)*4 + 2*h + ((j)&1); \
  f32x4 b_ = *(const f32x4*)(bsl + 16*Tg_ + 4*quad); \
  acc##j = b_ + __builtin_bit_cast(f32x4, wA##j##_0) * xvp4; }

// Gates: z' for i/f/o pre-scaled -> exp2 direct; g unscaled (relu only).
#define GATES(qp, Ai, Af, Ag, Ao, CST, SAVEK, HK) { \
  f32x4 ei_, ef_, eo_; \
  _Pragma("unroll") for (int r_ = 0; r_ < 4; ++r_) { \
    ei_[r_] = __builtin_amdgcn_exp2f(Ai[r_]); \
    ef_[r_] = __builtin_amdgcn_exp2f(Af[r_]); \
    eo_[r_] = __builtin_amdgcn_exp2f(Ao[r_]); \
  } \
  f32x4 si_, sf_, so_; \
  _Pragma("unroll") for (int r_ = 0; r_ < 4; ++r_) { \
    si_[r_] = __builtin_amdgcn_rcpf(1.0f + ei_[r_]); \
    sf_[r_] = __builtin_amdgcn_rcpf(1.0f + ef_[r_]); \
    so_[r_] = __builtin_amdgcn_rcpf(1.0f + eo_[r_]); \
  } \
  const f32x4 z4_ = {0.f, 0.f, 0.f, 0.f}; \
  f32x4 rg_ = __builtin_elementwise_max(Ag, z4_); \
  f32x4 cv_ = sf_ * CST + si_ * rg_; \
  CST = cv_; \
  f32x4 hv_ = so_ * __builtin_elementwise_max(cv_, z4_); \
  u32x2 pv_ = { pkf16(hv_[0], hv_[1]), pkf16(hv_[2], hv_[3]) }; \
  *(u32x2*)(hw_ + 16*(qp)) = pv_; \
  if (SAVEK) HK = hv_; }

#define GATE_SEG(tg_, SV_) { \
  __fp16* hw_ = hb_l + ((tg_)&7)*1152 + l15*72 + 32*h + 4*quad; \
  GATES(0, acc0, acc2, acc4, acc6, cst0, SV_, hK0) \
  GATES(1, acc1, acc3, acc5, acc7, cst1, SV_, hK1) }

// Spin-wait on a progress counter (workgroup-scope LDS atomic, cached locally).
#define WAITGE(cache, idx, need) \
  while ((cache) < (need)) \
    (cache) = __hip_atomic_load(&Pf[idx], __ATOMIC_ACQUIRE, __HIP_MEMORY_SCOPE_WORKGROUP);

// 64 blocks x 512 threads; block = 16 batch rows; 8 waves = 4 layers x 2 unit-halves.
// R27 = R26 base (577us steady, verified) + gates(t) || W(t+1) overlap via
// single-acc W-prefetch after publish + bias in LDS.
// Why this differs from failed R16: R16 kept TWO acc sets (wacc) -> 32 extra
// VGPRs -> scratch spill (WRITE_SIZE 3460->4612). Here acc is REUSED (U
// accumulates, gates consume, WPRE overwrites) and bias moved to LDS (-32
// regs). Input wait moves to t+2 post-publish (replaces top-of-step wait;
// ring guard t-7 still covers the early read -- algebra re-verified).
__global__ __launch_bounds__(512)
__attribute__((amdgpu_waves_per_eu(2, 2)))
void lstm_phase(
    const float* __restrict__ x,
    const float* __restrict__ Wx0, const float* __restrict__ U0, const float* __restrict__ b0,
    const float* __restrict__ Wx1, const float* __restrict__ U1, const float* __restrict__ b1,
    const float* __restrict__ Wx2, const float* __restrict__ U2, const float* __restrict__ b2,
    const float* __restrict__ Wx3, const float* __restrict__ U3, const float* __restrict__ b3,
    const float* __restrict__ Wd,  const float* __restrict__ bd,
    float* __restrict__ out)
{
    // dwords: hbuf f16 [0,18432) | x_s f32 [18432,27136) | red [27136,27168) |
    //         Pf [27168,27176) | bs [27176,28200)
    extern __shared__ uint32_t smem[];
    __fp16* hb16 = (__fp16*)smem;              // [l][slot8][row 16][unit 64 pad 72]
    float*  xs   = (float*)(smem + 18432);     // [t][17]
    float*  red  = (float*)(smem + 27136);     // [2][16] epilogue partials
    int*    Pf   = (int*)(smem + 27168);       // [8] per-wave progress counters
    float*  bs   = (float*)(smem + 27176);     // [l][256] pre-scaled bias

    const int tid  = threadIdx.x;
    const int lane = tid & 63;
    const int l15  = lane & 15;
    const int quad = lane >> 4;
    const int wv   = tid >> 6;
    const int l    = wv >> 1;                  // layer
    const int h    = wv & 1;                   // unit-half
    const int b0i  = blockIdx.x * 16;

    // ---- staging: zero hbuf + flags, stage x, pre-scaled bias table ----
    for (int i = tid; i < 27176; i += 512) smem[i] = 0;
    __syncthreads();
    for (int i = tid; i < 16 * TT; i += 512) {
        int row = i >> 9, t_ = i & (TT - 1);
        xs[t_ * 17 + row] = x[(b0i + row) * TT + t_];
    }
    for (int i = tid; i < 1024; i += 512) {
        int l_ = i >> 8, c_ = i & 255;
        const float* bsrc = (l_ == 0) ? b0 : (l_ == 1) ? b1 : (l_ == 2) ? b2 : b3;
        float sc_ = ((c_ >> 6) == 2) ? 1.0f : -1.4426950408889634f;
        bs[i] = bsrc[c_] * sc_;
    }

    const float* Uw   = (l == 0) ? U0 : (l == 1) ? U1 : (l == 2) ? U2 : U3;
    const float* Wsrc = (l == 1) ? Wx1 : (l == 2) ? Wx2 : (l == 3) ? Wx3 : U0;

    REP8(DECLT)
    REP8(LOADT)

    f32x4 acc0, acc1, acc2, acc3, acc4, acc5, acc6, acc7;
    f32x4 cst0 = {0,0,0,0}, cst1 = {0,0,0,0};
    f32x4 hK0  = {0,0,0,0}, hK1  = {0,0,0,0};

    __fp16* hb_l  = hb16 + l * 9216;           // own buffer (8 slots x 1152 f16)
    const __fp16* hb_in = hb16 + (l > 0 ? (l - 1) * 9216 : 0);
    const float*  bsl   = bs + l * 256;

    f16x8 xBp0 = {}, xBp1 = {};
    float xvp = 0.f;

    __syncthreads();

    int pA0 = 0, pA1 = 0, pP = 0, pC0 = 0, pC1 = 0;   // cached counter values

    // ---- prologue: acc = bias + W*in for t=0 ----
    if (l > 0) {
        WAITGE(pA0, 2*l - 2, 1)
        WAITGE(pA1, 2*l - 1, 1)
        const __fp16* xp_ = hb_in + 0 * 1152 + l15 * 72 + 8 * quad;
        xBp0 = *(const f16x8*)xp_;
        xBp1 = *(const f16x8*)(xp_ + 32);
        REP8(WPRE)
    } else {
        xvp = xs[l15];
        f32x4 xvp4 = {xvp, xvp, xvp, xvp};
        REP8(WPREX)
    }

    for (int t = 0; t < TT; ++t) {
        if (t > 0) WAITGE(pP, 2*l + 1 - h, t)
        if (l < 3 && t >= 8) {                 // ring-reuse guard (slot t&7 = h(t-8))
            WAITGE(pC0, 2*l + 2, t - 7)
            WAITGE(pC1, 2*l + 3, t - 7)
        }
        // ---- U phase: recurrence accumulates onto W-precomputed acc ----
        {
            const __fp16* hp_ = hb_l + ((t - 1) & 7) * 1152 + l15 * 72 + 8 * quad;
            f16x8 hB0 = *(const f16x8*)hp_;
            f16x8 hB1 = *(const f16x8*)(hp_ + 32);
            __builtin_amdgcn_s_setprio(1);
            REP8(MUA)
            REP8(MUB)
            __builtin_amdgcn_s_setprio(0);
        }
        // ---- gates(t) consume acc; publish ----
        {
            const bool sv_ = (l == 3) && (t == TT - 1);
            GATE_SEG(t, sv_)
        }
        __hip_atomic_store(&Pf[2*l + h], t + 1, __ATOMIC_RELEASE, __HIP_MEMORY_SCOPE_WORKGROUP);
        // ---- W-prefetch(t+1) overwrites acc; overlaps gates above ----
        if (t + 1 < TT) {
            if (l > 0) {
                WAITGE(pA0, 2*l - 2, t + 2)
                WAITGE(pA1, 2*l - 1, t + 2)
                const __fp16* xp_ = hb_in + ((t + 1) & 7) * 1152 + l15 * 72 + 8 * quad;
                xBp0 = *(const f16x8*)xp_;
                xBp1 = *(const f16x8*)(xp_ + 32);
                REP8(WPRE)
            } else {
                xvp = xs[(t + 1) * 17 + l15];
                f32x4 xvp4 = {xvp, xvp, xvp, xvp};
                REP8(WPREX)
            }
        }
    }

    __syncthreads();

    // dense epilogue: waves (3,h); lane holds h[511] f32 for units 32h+16q'+4quad+r, row l15
    if (l == 3) {
        float p = 0.f;
        #pragma unroll
        for (int r = 0; r < 4; ++r) {
            p += hK0[r] * Wd[32 * h + 4 * quad + r];
            p += hK1[r] * Wd[32 * h + 16 + 4 * quad + r];
        }
        p += __shfl_down(p, 32, 64);
        p += __shfl_down(p, 16, 64);
        if (lane < 16) red[h * 16 + lane] = p;
    }
    __syncthreads();
    if (wv == 6 && lane < 16) out[b0i + lane] = red[lane] + red[16 + lane] + bd[0];
}

extern "C" void kernel_launch(void* const* d_in, const int* in_sizes, int n_in,
                              void* d_out, int out_size, void* d_ws, size_t ws_size,
                              hipStream_t stream) {
    const float* x   = (const float*)d_in[0];
    const float* Wx0 = (const float*)d_in[1];
    const float* U0  = (const float*)d_in[2];
    const float* b0  = (const float*)d_in[3];
    const float* Wx1 = (const float*)d_in[4];
    const float* U1  = (const float*)d_in[5];
    const float* b1  = (const float*)d_in[6];
    const float* Wx2 = (const float*)d_in[7];
    const float* U2  = (const float*)d_in[8];
    const float* b2  = (const float*)d_in[9];
    const float* Wx3 = (const float*)d_in[10];
    const float* U3  = (const float*)d_in[11];
    const float* b3  = (const float*)d_in[12];
    const float* Wd  = (const float*)d_in[13];
    const float* bd  = (const float*)d_in[14];
    float* out = (float*)d_out;

    static const int kLds = 28200 * 4;   // 112800 B dynamic LDS
    (void)hipFuncSetAttribute((const void*)lstm_phase,
                              hipFuncAttributeMaxDynamicSharedMemorySize, kLds);
    hipLaunchKernelGGL(lstm_phase, dim3(64), dim3(512), kLds, stream,
                       x, Wx0, U0, b0, Wx1, U1, b1, Wx2, U2, b2, Wx3, U3, b3,
                       Wd, bd, out);
}

// Round 18
// 638.498 us; speedup vs baseline: 1.1257x; 1.1257x over previous
//
#include <hip/hip_runtime.h>
#include <stdint.h>

#define TT 512

typedef __fp16   f16x8  __attribute__((ext_vector_type(8)));
typedef float    f32x4  __attribute__((ext_vector_type(4)));
typedef __fp16   fp16x2 __attribute__((ext_vector_type(2)));
typedef uint32_t u32x2  __attribute__((ext_vector_type(2)));

__device__ __forceinline__ f32x4 mfma16(f16x8 a, f16x8 b, f32x4 c) {
    return __builtin_amdgcn_mfma_f32_16x16x32_f16(a, b, c, 0, 0, 0);
}
__device__ __forceinline__ uint32_t pkf16(float a, float b) {
    fp16x2 h = __builtin_amdgcn_cvt_pkrtz(a, b);
    return __builtin_bit_cast(uint32_t, h);
}

#define REP8(M) M(0)M(1)M(2)M(3)M(4)M(5)M(6)M(7)

// A-operand gather with per-column scale SC (weights transposed, z^T form):
// A[m=16T+l15][k=32F+8q+j] = SRC[k][16T+l15] * SC
#define GA(SRC, T, F, SC) (f16x8){ \
  (__fp16)((SRC)[(32*(F)+8*quad+0)*256 + 16*(T)+l15] * (SC)), \
  (__fp16)((SRC)[(32*(F)+8*quad+1)*256 + 16*(T)+l15] * (SC)), \
  (__fp16)((SRC)[(32*(F)+8*quad+2)*256 + 16*(T)+l15] * (SC)), \
  (__fp16)((SRC)[(32*(F)+8*quad+3)*256 + 16*(T)+l15] * (SC)), \
  (__fp16)((SRC)[(32*(F)+8*quad+4)*256 + 16*(T)+l15] * (SC)), \
  (__fp16)((SRC)[(32*(F)+8*quad+5)*256 + 16*(T)+l15] * (SC)), \
  (__fp16)((SRC)[(32*(F)+8*quad+6)*256 + 16*(T)+l15] * (SC)), \
  (__fp16)((SRC)[(32*(F)+8*quad+7)*256 + 16*(T)+l15] * (SC)) }

// Wave (l,h) owns zcols {64g + 32h + 16q' .. +15}: local j = 2g+q' -> tile Tg.
// Gate index = j>>1 (0:i 1:f 2:g 3:o). i/f/o columns+bias pre-scaled by -log2e
// at load time (R19 fold).
#define DECLT(j) f16x8 uA##j##_0, uA##j##_1, wA##j##_0, wA##j##_1; f32x4 bias##j;
#define LOADT(j) { \
  const int Tg_ = ((j)>>1)*4 + 2*h + ((j)&1); \
  const float sc_ = (((j)>>1) == 2) ? 1.0f : -1.4426950408889634f; \
  uA##j##_0 = GA(Uw, Tg_, 0, sc_); uA##j##_1 = GA(Uw, Tg_, 1, sc_); \
  bias##j = (f32x4){ bw_[16*Tg_ + 4*quad + 0] * sc_, bw_[16*Tg_ + 4*quad + 1] * sc_, \
                     bw_[16*Tg_ + 4*quad + 2] * sc_, bw_[16*Tg_ + 4*quad + 3] * sc_ }; \
  if (l > 0) { wA##j##_0 = GA(Wsrc, Tg_, 0, sc_); wA##j##_1 = GA(Wsrc, Tg_, 1, sc_); } \
  else { wA##j##_0 = __builtin_bit_cast(f16x8, (f32x4){ \
           Wx0[16*Tg_+4*quad+0] * sc_, Wx0[16*Tg_+4*quad+1] * sc_, \
           Wx0[16*Tg_+4*quad+2] * sc_, Wx0[16*Tg_+4*quad+3] * sc_ }); \
         wA##j##_1 = wA##j##_0; } }

// MFMA segment: hB ds_read hoisted at top (latency hides under the 16
// partner-independent W-MFMAs that follow) -- R14's proven order, untouched.
// Third confirmation this round (R17/R18/R27 all regressed): do NOT reorder.
#define MW0(j) acc##j = mfma16(wA##j##_0, xBp0, bias##j);
#define MW1(j) acc##j = mfma16(wA##j##_1, xBp1, acc##j);
#define MX(j)  acc##j = bias##j + __builtin_bit_cast(f32x4, wA##j##_0) * xvp4;
#define MU0(j) acc##j = mfma16(uA##j##_0, hB0, acc##j);
#define MU1(j) acc##j = mfma16(uA##j##_1, hB1, acc##j);

#define MFMA_SEG(t_) { \
  const __fp16* hp_ = hb_l + (((t_)-1)&7)*1152 + l15*72 + 8*quad; \
  f16x8 hB0 = *(const f16x8*)hp_; \
  f16x8 hB1 = *(const f16x8*)(hp_ + 32); \
  if (l > 0) { REP8(MW0) REP8(MW1) } \
  else       { f32x4 xvp4 = {xvp, xvp, xvp, xvp}; REP8(MX) } \
  REP8(MU0) \
  REP8(MU1) }

// Gates: z' for i/f/o pre-scaled -> exp2 direct; g unscaled (relu only).
#define GATES(qp, Ai, Af, Ag, Ao, CST, SAVEK, HK) { \
  f32x4 ei_, ef_, eo_; \
  _Pragma("unroll") for (int r_ = 0; r_ < 4; ++r_) { \
    ei_[r_] = __builtin_amdgcn_exp2f(Ai[r_]); \
    ef_[r_] = __builtin_amdgcn_exp2f(Af[r_]); \
    eo_[r_] = __builtin_amdgcn_exp2f(Ao[r_]); \
  } \
  f32x4 si_, sf_, so_; \
  _Pragma("unroll") for (int r_ = 0; r_ < 4; ++r_) { \
    si_[r_] = __builtin_amdgcn_rcpf(1.0f + ei_[r_]); \
    sf_[r_] = __builtin_amdgcn_rcpf(1.0f + ef_[r_]); \
    so_[r_] = __builtin_amdgcn_rcpf(1.0f + eo_[r_]); \
  } \
  const f32x4 z4_ = {0.f, 0.f, 0.f, 0.f}; \
  f32x4 rg_ = __builtin_elementwise_max(Ag, z4_); \
  f32x4 cv_ = sf_ * CST + si_ * rg_; \
  CST = cv_; \
  f32x4 hv_ = so_ * __builtin_elementwise_max(cv_, z4_); \
  u32x2 pv_ = { pkf16(hv_[0], hv_[1]), pkf16(hv_[2], hv_[3]) }; \
  *(u32x2*)(hw_ + 16*(qp)) = pv_; \
  if (SAVEK) HK = hv_; }

#define GATE_SEG(tg_, SV_) { \
  __fp16* hw_ = hb_l + ((tg_)&7)*1152 + l15*72 + 32*h + 4*quad; \
  GATES(0, acc0, acc2, acc4, acc6, cst0, SV_, hK0) \
  GATES(1, acc1, acc3, acc5, acc7, cst1, SV_, hK1) }

// Spin-wait on a progress counter (workgroup-scope LDS atomic, cached locally).
#define WAITGE(cache, idx, need) \
  while ((cache) < (need)) \
    (cache) = __hip_atomic_load(&Pf[idx], __ATOMIC_ACQUIRE, __HIP_MEMORY_SCOPE_WORKGROUP);

// 64 blocks x 512 threads; block = 16 batch rows; 8 waves = 4 layers x 2 unit-halves.
// R28 = BYTE-EXACT RESTORE of R26/R20 (best verified: 577us steady / 638 headline).
// Final session ledger (17 rounds, 12 mechanisms): async flag decoupling +7%
// (R14), setprio +2.5% (R20); exp2 fold neutral (R19); in-step reorders x3
// negative (R17/R18/R27 -- U-phase adjacent to partner-wait always loses);
// s_sleep -3% (R24); 4 waves/SIMD register-infeasible (R21-R23); 1 wave/SIMD
// 2x worse (R15); layer-parallel global ring 15x worse (R25). Structure:
// latency-bound on the recurrence chain (~2705 cyc/step vs ~1240 matrix floor);
// 2 waves/SIMD forced by ~200-reg working set; 64 blocks forced by batch/16.
__global__ __launch_bounds__(512)
__attribute__((amdgpu_waves_per_eu(2, 2)))
void lstm_phase(
    const float* __restrict__ x,
    const float* __restrict__ Wx0, const float* __restrict__ U0, const float* __restrict__ b0,
    const float* __restrict__ Wx1, const float* __restrict__ U1, const float* __restrict__ b1,
    const float* __restrict__ Wx2, const float* __restrict__ U2, const float* __restrict__ b2,
    const float* __restrict__ Wx3, const float* __restrict__ U3, const float* __restrict__ b3,
    const float* __restrict__ Wd,  const float* __restrict__ bd,
    float* __restrict__ out)
{
    // dwords: hbuf f16 [0,18432) | x_s f32 [18432,27136) | red [27136,27168) | P [27168,27176)
    extern __shared__ uint32_t smem[];
    __fp16* hb16 = (__fp16*)smem;              // [l][slot8][row 16][unit 64 pad 72]
    float*  xs   = (float*)(smem + 18432);     // [t][17]
    float*  red  = (float*)(smem + 27136);     // [2][16] epilogue partials
    int*    Pf   = (int*)(smem + 27168);       // [8] per-wave progress counters

    const int tid  = threadIdx.x;
    const int lane = tid & 63;
    const int l15  = lane & 15;
    const int quad = lane >> 4;
    const int wv   = tid >> 6;
    const int l    = wv >> 1;                  // layer
    const int h    = wv & 1;                   // unit-half
    const int b0i  = blockIdx.x * 16;

    // ---- staging: zero hbuf + flags, stage x ----
    for (int i = tid; i < 27176; i += 512) smem[i] = 0;
    __syncthreads();
    for (int i = tid; i < 16 * TT; i += 512) {
        int row = i >> 9, t_ = i & (TT - 1);
        xs[t_ * 17 + row] = x[(b0i + row) * TT + t_];
    }

    const float* Uw   = (l == 0) ? U0 : (l == 1) ? U1 : (l == 2) ? U2 : U3;
    const float* bw_  = (l == 0) ? b0 : (l == 1) ? b1 : (l == 2) ? b2 : b3;
    const float* Wsrc = (l == 1) ? Wx1 : (l == 2) ? Wx2 : (l == 3) ? Wx3 : U0;

    REP8(DECLT)
    REP8(LOADT)

    f32x4 acc0, acc1, acc2, acc3, acc4, acc5, acc6, acc7;
    f32x4 cst0 = {0,0,0,0}, cst1 = {0,0,0,0};
    f32x4 hK0  = {0,0,0,0}, hK1  = {0,0,0,0};

    __fp16* hb_l  = hb16 + l * 9216;           // own buffer (8 slots x 1152 f16)
    const __fp16* hb_in = hb16 + (l > 0 ? (l - 1) * 9216 : 0);

    f16x8 xBp0 = {}, xBp1 = {};
    float xvp = 0.f;

    __syncthreads();

    if (l == 0) xvp = xs[l15];                 // layer-0 operand for t=0

    int pA0 = 0, pA1 = 0, pP = 0, pC0 = 0, pC1 = 0;   // cached counter values

    for (int t = 0; t < TT; ++t) {
        if (l > 0) {
            WAITGE(pA0, 2*l - 2, t + 1)
            WAITGE(pA1, 2*l - 1, t + 1)
            const __fp16* xp_ = hb_in + (t & 7) * 1152 + l15 * 72 + 8 * quad;
            xBp0 = *(const f16x8*)xp_;
            xBp1 = *(const f16x8*)(xp_ + 32);
        }
        if (t > 0) WAITGE(pP, 2*l + 1 - h, t)
        if (l < 3 && t >= 8) {                 // ring-reuse guard (slot t&7 = h(t-8))
            WAITGE(pC0, 2*l + 2, t - 7)
            WAITGE(pC1, 2*l + 3, t - 7)
        }
        __builtin_amdgcn_s_setprio(1);
        MFMA_SEG(t)
        __builtin_amdgcn_s_setprio(0);
        {
            const bool sv_ = (l == 3) && (t == TT - 1);
            GATE_SEG(t, sv_)
        }
        __hip_atomic_store(&Pf[2*l + h], t + 1, __ATOMIC_RELEASE, __HIP_MEMORY_SCOPE_WORKGROUP);
        if (l == 0 && t + 1 < TT) xvp = xs[(t + 1) * 17 + l15];
    }

    __syncthreads();

    // dense epilogue: waves (3,h); lane holds h[511] f32 for units 32h+16q'+4quad+r, row l15
    if (l == 3) {
        float p = 0.f;
        #pragma unroll
        for (int r = 0; r < 4; ++r) {
            p += hK0[r] * Wd[32 * h + 4 * quad + r];
            p += hK1[r] * Wd[32 * h + 16 + 4 * quad + r];
        }
        p += __shfl_down(p, 32, 64);
        p += __shfl_down(p, 16, 64);
        if (lane < 16) red[h * 16 + lane] = p;
    }
    __syncthreads();
    if (wv == 6 && lane < 16) out[b0i + lane] = red[lane] + red[16 + lane] + bd[0];
}

extern "C" void kernel_launch(void* const* d_in, const int* in_sizes, int n_in,
                              void* d_out, int out_size, void* d_ws, size_t ws_size,
                              hipStream_t stream) {
    const float* x   = (const float*)d_in[0];
    const float* Wx0 = (const float*)d_in[1];
    const float* U0  = (const float*)d_in[2];
    const float* b0  = (const float*)d_in[3];
    const float* Wx1 = (const float*)d_in[4];
    const float* U1  = (const float*)d_in[5];
    const float* b1  = (const float*)d_in[6];
    const float* Wx2 = (const float*)d_in[7];
    const float* U2  = (const float*)d_in[8];
    const float* b2  = (const float*)d_in[9];
    const float* Wx3 = (const float*)d_in[10];
    const float* U3  = (const float*)d_in[11];
    const float* b3  = (const float*)d_in[12];
    const float* Wd  = (const float*)d_in[13];
    const float* bd  = (const float*)d_in[14];
    float* out = (float*)d_out;

    static const int kLds = 27176 * 4;   // 108704 B dynamic LDS
    (void)hipFuncSetAttribute((const void*)lstm_phase,
                              hipFuncAttributeMaxDynamicSharedMemorySize, kLds);
    hipLaunchKernelGGL(lstm_phase, dim3(64), dim3(512), kLds, stream,
                       x, Wx0, U0, b0, Wx1, U1, b1, Wx2, U2, b2, Wx3, U3, b3,
                       Wd, bd, out);
}